// Round 1
// baseline (231.740 us; speedup 1.0000x reference)
//
#include <hip/hip_runtime.h>

typedef _Float16 f16;
typedef __attribute__((ext_vector_type(8))) _Float16 f16x8;
typedef __attribute__((ext_vector_type(4))) float f32x4;

#define DI __device__ __forceinline__

constexpr int BB = 2, SS = 2048, HH = 1024;
constexpr int NQ = 16, NKV = 4, HD = 64;
constexpr int NTOK = BB * SS;            // 4096
constexpr int NQKV = NQ*HD + 2*NKV*HD;   // 1536
constexpr float ATTN_SCALE = 0.125f;

DI f32x4 zero4() { f32x4 z = {0.f, 0.f, 0.f, 0.f}; return z; }

// Load one MFMA operand fragment (A-style: row = l&15 entry, k = kbase+4g+(j&3)+16(j>>2))
DI f16x8 ldfrag(const f16* sh, int stride, int row, int g, int kbase) {
  union { uint2 u[2]; f16x8 v; } x;
  const f16* p = sh + row*stride + kbase + 4*g;
  x.u[0] = *reinterpret_cast<const uint2*>(p);
  x.u[1] = *reinterpret_cast<const uint2*>(p + 16);
  return x.v;
}

// ---------------- prep: effective weights, x->fp16, rope tables ----------------
__global__ __launch_bounds__(256) void prep_kernel(
    const float* __restrict__ x,
    const float* __restrict__ Wq, const float* __restrict__ Wk,
    const float* __restrict__ Wv, const float* __restrict__ Wo,
    const float* __restrict__ qA, const float* __restrict__ qB,
    const float* __restrict__ kA, const float* __restrict__ kB,
    const float* __restrict__ vA, const float* __restrict__ vB,
    const float* __restrict__ oA, const float* __restrict__ oB,
    f16* __restrict__ xh, f16* __restrict__ Wqkv, f16* __restrict__ Woe,
    float* __restrict__ ctab, float* __restrict__ stab) {
  int idx = blockIdx.x * 256 + threadIdx.x;
  if (idx < NQKV * HH) {
    int n = idx >> 10, hcol = idx & 1023;
    const float *Am, *Bm; float wv; int nn;
    if (n < 1024)      { nn = n;        wv = Wq[idx];              Am = qA; Bm = qB; }
    else if (n < 1280) { nn = n - 1024; wv = Wk[nn*1024 + hcol];   Am = kA; Bm = kB; }
    else               { nn = n - 1280; wv = Wv[nn*1024 + hcol];   Am = vA; Bm = vB; }
    float s = 0.f;
#pragma unroll
    for (int r = 0; r < 8; ++r) s += Bm[nn*8 + r] * Am[r*1024 + hcol];
    Wqkv[idx] = (f16)(wv + 2.0f * s);
  } else if ((idx -= NQKV * HH) < 1024 * 1024) {
    int n = idx >> 10, hcol = idx & 1023;
    float s = 0.f;
#pragma unroll
    for (int r = 0; r < 8; ++r) s += oB[n*8 + r] * oA[r*1024 + hcol];
    Woe[idx] = (f16)(Wo[idx] + 2.0f * s);
  } else if ((idx -= 1024 * 1024) < NTOK * HH) {
    xh[idx] = (f16)x[idx];
  } else if ((idx -= NTOK * HH) < SS * 32) {
    int s = idx >> 5, d = idx & 31;
    float inv = expf(-(float)d * 0.28782313662425583f);  // ln(10000)/32
    float ang = (float)s * inv;
    ctab[idx] = cosf(ang);
    stab[idx] = sinf(ang);
  }
}

// ---------------- GEMM: C[M][N] = A[M][K] * Bw[N][K]^T ----------------
template<typename OUT_T>
__global__ __launch_bounds__(256) void gemm_bt(const f16* __restrict__ A, const f16* __restrict__ Bw,
                                               OUT_T* __restrict__ C, int M, int N, int K) {
  __shared__ f16 Ash[128 * 40];
  __shared__ f16 Bsh[128 * 40];
  const int nt = N >> 7;
  const int m0 = (blockIdx.x / nt) << 7;
  const int n0 = (blockIdx.x % nt) << 7;
  const int tid = threadIdx.x;
  const int lane = tid & 63;
  const int w = tid >> 6, wr = w >> 1, wc = w & 1;
  const int l15 = lane & 15, g = lane >> 4;

  f32x4 acc[4][4];
#pragma unroll
  for (int i = 0; i < 4; ++i)
#pragma unroll
    for (int j = 0; j < 4; ++j) acc[i][j] = zero4();

  uint4 ra[2], rb[2];
  auto load_regs = [&](int kb) {
#pragma unroll
    for (int l = 0; l < 2; ++l) {
      int idx = (l << 8) + tid;
      int row = idx >> 2, k8 = (idx & 3) << 3;
      ra[l] = *reinterpret_cast<const uint4*>(A  + (size_t)(m0 + row) * K + kb + k8);
      rb[l] = *reinterpret_cast<const uint4*>(Bw + (size_t)(n0 + row) * K + kb + k8);
    }
  };
  load_regs(0);
  for (int kb = 0; kb < K; kb += 32) {
    __syncthreads();
#pragma unroll
    for (int l = 0; l < 2; ++l) {
      int idx = (l << 8) + tid;
      int row = idx >> 2, k8 = (idx & 3) << 3;
      *reinterpret_cast<uint4*>(Ash + row * 40 + k8) = ra[l];
      *reinterpret_cast<uint4*>(Bsh + row * 40 + k8) = rb[l];
    }
    __syncthreads();
    if (kb + 32 < K) load_regs(kb + 32);
    f16x8 af[4], bf[4];
#pragma unroll
    for (int mi = 0; mi < 4; ++mi) af[mi] = ldfrag(Ash, 40, (wr << 6) + (mi << 4) + l15, g, 0);
#pragma unroll
    for (int nj = 0; nj < 4; ++nj) bf[nj] = ldfrag(Bsh, 40, (wc << 6) + (nj << 4) + l15, g, 0);
#pragma unroll
    for (int mi = 0; mi < 4; ++mi)
#pragma unroll
      for (int nj = 0; nj < 4; ++nj)
        acc[mi][nj] = __builtin_amdgcn_mfma_f32_16x16x32_f16(af[mi], bf[nj], acc[mi][nj], 0, 0, 0);
  }
#pragma unroll
  for (int mi = 0; mi < 4; ++mi)
#pragma unroll
    for (int nj = 0; nj < 4; ++nj) {
      int mmb = m0 + (wr << 6) + (mi << 4) + (g << 2);
      int nn  = n0 + (wc << 6) + (nj << 4) + l15;
      f32x4 a = acc[mi][nj];
#pragma unroll
      for (int r = 0; r < 4; ++r) C[(size_t)(mmb + r) * N + nn] = (OUT_T)a[r];
    }
}

// ---------------- RoPE + layout to (B,H,S,D) ----------------
__global__ __launch_bounds__(256) void rope_kernel(const f16* __restrict__ qkv,
    const float* __restrict__ ctab, const float* __restrict__ stab,
    f16* __restrict__ Qr, f16* __restrict__ Kr) {
  int idx = blockIdx.x * 256 + threadIdx.x;   // (((b*S+s)*20)+hh)*32+dp
  int dp = idx & 31;
  int t = idx >> 5;
  int hh = t % 20;
  int tok = t / 20;
  int s = tok & (SS - 1), b = tok >> 11;
  float c  = ctab[(s << 5) + dp];
  float sn = stab[(s << 5) + dp];
  const f16* row = qkv + (size_t)tok * NQKV;
  float x1, x2; f16* out;
  if (hh < 16) {
    x1 = (float)row[hh*64 + 2*dp]; x2 = (float)row[hh*64 + 2*dp + 1];
    out = Qr + ((size_t)(b*NQ + hh)*SS + s) * HD;
  } else {
    int hk = hh - 16;
    x1 = (float)row[1024 + hk*64 + 2*dp]; x2 = (float)row[1024 + hk*64 + 2*dp + 1];
    out = Kr + ((size_t)(b*NKV + hk)*SS + s) * HD;
  }
  out[dp]      = (f16)(x1*c  - x2*sn);
  out[dp + 32] = (f16)(x1*sn + x2*c);
}

// ---------------- flash attention (swapped-operand, GQA) ----------------
__global__ __launch_bounds__(256) void attn_kernel(
    const f16* __restrict__ Qr, const f16* __restrict__ Kr,
    const f16* __restrict__ qkv, f16* __restrict__ AO) {
  __shared__ f16 Qs[64 * 72];
  __shared__ f16 Ks[64 * 72];
  __shared__ f16 Vs[64 * 68];
  const int tid = threadIdx.x, lane = tid & 63, w = tid >> 6;
  const int l15 = lane & 15, g = lane >> 4;
  const int bh = blockIdx.x;
  const int b = bh >> 4, h = bh & 15, hkv = h >> 2;
  const int q0 = blockIdx.y << 6;
  const f16* Qbase = Qr + ((size_t)(b*NQ + h)*SS + q0) * HD;
  const f16* Kbase = Kr + (size_t)(b*NKV + hkv) * SS * HD;
  {
    int row = tid >> 2, d0 = (tid & 3) << 4;
    const f16* src = Qbase + row * HD + d0;
    uint4 v0 = *reinterpret_cast<const uint4*>(src);
    uint4 v1 = *reinterpret_cast<const uint4*>(src + 8);
    *reinterpret_cast<uint4*>(Qs + row * 72 + d0) = v0;
    *reinterpret_cast<uint4*>(Qs + row * 72 + d0 + 8) = v1;
  }
  __syncthreads();
  const f16x8 qf0 = ldfrag(Qs, 72, (w << 4) + l15, g, 0);
  const f16x8 qf1 = ldfrag(Qs, 72, (w << 4) + l15, g, 32);
  f32x4 acc[4];
#pragma unroll
  for (int i = 0; i < 4; ++i) acc[i] = zero4();
  float mrun = -3e38f, ell = 0.f;

  for (int kv0 = 0; kv0 < SS; kv0 += 64) {
    __syncthreads();
    { // stage K tile [64 kv][64 d]
      int row = tid >> 2, d0 = (tid & 3) << 4;
      const f16* src = Kbase + (size_t)(kv0 + row) * HD + d0;
      uint4 v0 = *reinterpret_cast<const uint4*>(src);
      uint4 v1 = *reinterpret_cast<const uint4*>(src + 8);
      *reinterpret_cast<uint4*>(Ks + row * 72 + d0) = v0;
      *reinterpret_cast<uint4*>(Ks + row * 72 + d0 + 8) = v1;
    }
    { // stage V transposed: Vs[d][s_local]
      int s0 = (tid >> 3) << 1, dd0 = (tid & 7) << 3;
      const f16* src0 = qkv + (size_t)(b*SS + kv0 + s0) * NQKV + 1280 + hkv*64 + dd0;
      union { uint4 u; f16 hh2[8]; } r0, r1;
      r0.u = *reinterpret_cast<const uint4*>(src0);
      r1.u = *reinterpret_cast<const uint4*>(src0 + NQKV);
#pragma unroll
      for (int j = 0; j < 8; ++j) {
        union { f16 hv[2]; unsigned u; } p;
        p.hv[0] = r0.hh2[j]; p.hv[1] = r1.hh2[j];
        *reinterpret_cast<unsigned*>(Vs + (dd0 + j) * 68 + s0) = p.u;
      }
    }
    __syncthreads();
    // S^T = K * Q^T  (lane holds col q=l15, rows kv=16*mb+4g+r)
    f32x4 sf[4];
#pragma unroll
    for (int mb = 0; mb < 4; ++mb) {
      f16x8 kf0 = ldfrag(Ks, 72, (mb << 4) + l15, g, 0);
      f16x8 kf1 = ldfrag(Ks, 72, (mb << 4) + l15, g, 32);
      f32x4 z = zero4();
      z = __builtin_amdgcn_mfma_f32_16x16x32_f16(kf0, qf0, z, 0, 0, 0);
      z = __builtin_amdgcn_mfma_f32_16x16x32_f16(kf1, qf1, z, 0, 0, 0);
      sf[mb] = z;
    }
    float tmax = -3e38f;
#pragma unroll
    for (int mb = 0; mb < 4; ++mb)
#pragma unroll
      for (int r = 0; r < 4; ++r) {
        float v = sf[mb][r] * ATTN_SCALE;
        sf[mb][r] = v;
        tmax = fmaxf(tmax, v);
      }
    tmax = fmaxf(tmax, __shfl_xor(tmax, 16));
    tmax = fmaxf(tmax, __shfl_xor(tmax, 32));
    float mnew = fmaxf(mrun, tmax);
    float corr = __expf(mrun - mnew);
    mrun = mnew;
    union { f16 hv[16]; f16x8 v[2]; } ph;
    float tsum = 0.f;
#pragma unroll
    for (int mb = 0; mb < 4; ++mb)
#pragma unroll
      for (int r = 0; r < 4; ++r) {
        float p = __expf(sf[mb][r] - mnew);
        tsum += p;
        ph.hv[mb*4 + r] = (f16)p;
      }
    tsum += __shfl_xor(tsum, 16);
    tsum += __shfl_xor(tsum, 32);
    ell = ell * corr + tsum;
    // out^T += V^T * P^T
#pragma unroll
    for (int db = 0; db < 4; ++db) {
      f16x8 vf0 = ldfrag(Vs, 68, (db << 4) + l15, g, 0);
      f16x8 vf1 = ldfrag(Vs, 68, (db << 4) + l15, g, 32);
      f32x4 a = acc[db];
#pragma unroll
      for (int r = 0; r < 4; ++r) a[r] *= corr;
      a = __builtin_amdgcn_mfma_f32_16x16x32_f16(vf0, ph.v[0], a, 0, 0, 0);
      a = __builtin_amdgcn_mfma_f32_16x16x32_f16(vf1, ph.v[1], a, 0, 0, 0);
      acc[db] = a;
    }
  }
  float inv = 1.0f / ell;
  int sg = q0 + (w << 4) + l15;
  size_t obase = ((size_t)b * SS + sg) * 1024 + h * 64;
#pragma unroll
  for (int db = 0; db < 4; ++db) {
    union { f16 hv[4]; uint2 u; } o;
#pragma unroll
    for (int r = 0; r < 4; ++r) o.hv[r] = (f16)(acc[db][r] * inv);
    *reinterpret_cast<uint2*>(AO + obase + (db << 4) + (g << 2)) = o.u;
  }
}

// ---------------- launch ----------------
extern "C" void kernel_launch(void* const* d_in, const int* in_sizes, int n_in,
                              void* d_out, int out_size, void* d_ws, size_t ws_size,
                              hipStream_t stream) {
  const float* x  = (const float*)d_in[0];
  const float* Wq = (const float*)d_in[1];
  const float* Wk = (const float*)d_in[2];
  const float* Wv = (const float*)d_in[3];
  const float* Wo = (const float*)d_in[4];
  const float* qA = (const float*)d_in[5];
  const float* qB = (const float*)d_in[6];
  const float* kA = (const float*)d_in[7];
  const float* kB = (const float*)d_in[8];
  const float* vA = (const float*)d_in[9];
  const float* vB = (const float*)d_in[10];
  const float* oA = (const float*)d_in[11];
  const float* oB = (const float*)d_in[12];
  char* ws = (char*)d_ws;
  f16* xh    = (f16*)(ws);                  // 8 MB
  f16* Wqkv  = (f16*)(ws + 8388608);        // 3 MB
  f16* Woe   = (f16*)(ws + 11534336);       // 2 MB
  f16* qkv   = (f16*)(ws + 13631488);       // 12 MB
  f16* Qr    = (f16*)(ws + 26214400);       // 8 MB
  f16* Kr    = (f16*)(ws + 34603008);       // 2 MB
  f16* AO    = (f16*)(ws + 36700160);       // 8 MB
  float* ctab = (float*)(ws + 45088768);    // 256 KB
  float* stab = (float*)(ws + 45350912);    // 256 KB
  float* out = (float*)d_out;

  prep_kernel<<<26880, 256, 0, stream>>>(x, Wq, Wk, Wv, Wo, qA, qB, kA, kB, vA, vB, oA, oB,
                                         xh, Wqkv, Woe, ctab, stab);
  gemm_bt<f16><<<dim3(32 * 12), 256, 0, stream>>>(xh, Wqkv, qkv, 4096, 1536, 1024);
  rope_kernel<<<10240, 256, 0, stream>>>(qkv, ctab, stab, Qr, Kr);
  attn_kernel<<<dim3(32, 32), 256, 0, stream>>>(Qr, Kr, qkv, AO);
  gemm_bt<float><<<dim3(32 * 8), 256, 0, stream>>>(AO, Woe, out, 4096, 1024, 1024);
}